// Round 9
// baseline (97.627 us; speedup 1.0000x reference)
//
#include <hip/hip_runtime.h>
#include <cmath>

#define NHEADS 8
#define HDIM 128
#define SPAN 24
#define U_ 16
#define W_ 128
#define C_ 151
#define HID 1024

typedef unsigned short ushort8v __attribute__((ext_vector_type(8)));
typedef unsigned short ushort4v __attribute__((ext_vector_type(4)));
typedef __bf16 bf16x8 __attribute__((ext_vector_type(8)));
typedef float f32x4 __attribute__((ext_vector_type(4)));

__device__ inline unsigned short f2bf(float f) {
    union { float f; unsigned u; } v; v.f = f;
    unsigned r = v.u + 0x7FFFu + ((v.u >> 16) & 1u);
    return (unsigned short)(r >> 16);
}
__device__ inline float bf2f(unsigned short u) {
    union { unsigned u; float f; } v; v.u = ((unsigned)u) << 16;
    return v.f;
}
__device__ inline ushort8v cvt8(float4 a, float4 b) {
    ushort8v v;
    v[0] = f2bf(a.x); v[1] = f2bf(a.y); v[2] = f2bf(a.z); v[3] = f2bf(a.w);
    v[4] = f2bf(b.x); v[5] = f2bf(b.y); v[6] = f2bf(b.z); v[7] = f2bf(b.w);
    return v;
}

// lgkm-only barrier: orders LDS producer->consumer without draining vmcnt.
#define BAR() asm volatile("s_waitcnt lgkmcnt(0)\n\ts_barrier" ::: "memory")

// ---- kernel 1: partial column sums of pos_proj (256 blocks x 64 thr) ----
__global__ void k_partial(const float* __restrict__ pp, float* __restrict__ part) {
    const int bi = blockIdx.x >> 2, cj = blockIdx.x & 3;
    const int col = cj * 256 + threadIdx.x * 4;
    const int row0 = bi * 16;
    float4 s = make_float4(0.f, 0.f, 0.f, 0.f);
    #pragma unroll
    for (int i = 0; i < 16; ++i) {
        float4 v = *(const float4*)(pp + (size_t)(row0 + i) * HID + col);
        s.x += v.x; s.y += v.y; s.z += v.z; s.w += v.w;
    }
    *(float4*)(part + (size_t)bi * HID + col) = s;
}

struct SC { float s[SPAN]; float c[SPAN]; };

// ---- main kernel: 2048 blocks x 256 thr (4 waves), 64 Q rows x 176 each.
// 4 independent barrier-groups per CU (vs 2 with 512-thr blocks).
// LDS: buf0 [0,8192) buf1 [8192,16384) aux(redp/s12)/bd [16384,+3584).
#define CHUNK_B 8192
#define AUX_OFF 16384
#define S12_OFF (AUX_OFF + 2048)
#define BD_PITCH 25

__device__ inline ushort8v emb8(const char* lds_raw, int f, int u16, const SC& sc) {
    float4 s1a = *(const float4*)(lds_raw + S12_OFF + u16 * 32);
    float4 s1b = *(const float4*)(lds_raw + S12_OFF + u16 * 32 + 16);
    float4 s2a = *(const float4*)(lds_raw + S12_OFF + 512 + u16 * 32);
    float4 s2b = *(const float4*)(lds_raw + S12_OFF + 512 + u16 * 32 + 16);
    const float sf = sc.s[f], cf = sc.c[f];
    ushort8v v;
    v[0] = f2bf(sf * s1a.x + cf * s2a.x); v[1] = f2bf(sf * s1a.y + cf * s2a.y);
    v[2] = f2bf(sf * s1a.z + cf * s2a.z); v[3] = f2bf(sf * s1a.w + cf * s2a.w);
    v[4] = f2bf(sf * s1b.x + cf * s2b.x); v[5] = f2bf(sf * s1b.y + cf * s2b.y);
    v[6] = f2bf(sf * s1b.z + cf * s2b.z); v[7] = f2bf(sf * s1b.w + cf * s2b.w);
    return v;
}

// chunk c = K_ext rows 32c..32c+31; thread covers rows rl and rl+16, unit u16.
#define ISSUE_K(c, PA0, PA1, PB0, PB1)                                         \
    {                                                                          \
        const int rA_ = 32 * (c) + rl;                                         \
        const int rB_ = rA_ + 16;                                              \
        if (rA_ < C_) {                                                        \
            const float* s_ = k + kbase + (size_t)rA_ * HID + u16 * 8;         \
            PA0 = *(const float4*)s_; PA1 = *(const float4*)(s_ + 4);          \
        }                                                                      \
        if (rB_ < C_) {                                                        \
            const float* s_ = k + kbase + (size_t)rB_ * HID + u16 * 8;         \
            PB0 = *(const float4*)s_; PB1 = *(const float4*)(s_ + 4);          \
        }                                                                      \
    }

#define WRITE_PURE(PA0, PA1, PB0, PB1, BUFOFF)                                 \
    {                                                                          \
        const int dA_ = (BUFOFF) + rl * 256 + ((u16 * 16) ^ ((rl & 7) << 4));  \
        *(ushort8v*)(lds_raw + dA_) = cvt8(PA0, PA1);                          \
        const int rB_ = rl + 16;                                               \
        const int dB_ = (BUFOFF) + rB_ * 256 + ((u16 * 16) ^ ((rB_ & 7) << 4));\
        *(ushort8v*)(lds_raw + dB_) = cvt8(PB0, PB1);                          \
    }

// chunk 4 = rows 128..159: row A (128..143) pure K; row B (144..159) K or emb
#define WRITE_C4(PA0, PA1, PB0, PB1, BUFOFF)                                   \
    {                                                                          \
        const int dA_ = (BUFOFF) + rl * 256 + ((u16 * 16) ^ ((rl & 7) << 4));  \
        *(ushort8v*)(lds_raw + dA_) = cvt8(PA0, PA1);                          \
        const int rB_ = rl + 16;                                               \
        const int rG_ = 144 + rl;                                              \
        const int dB_ = (BUFOFF) + rB_ * 256 + ((u16 * 16) ^ ((rB_ & 7) << 4));\
        ushort8v v_;                                                           \
        if (rG_ < C_) v_ = cvt8(PB0, PB1);                                     \
        else          v_ = emb8(lds_raw, rG_ - C_, u16, sc);                   \
        *(ushort8v*)(lds_raw + dB_) = v_;                                      \
    }

// chunk 5 = rows 160..175 (16 rows): emb f=9..23, row 175 zero
#define WRITE_C5(BUFOFF)                                                       \
    {                                                                          \
        const int rG_ = 160 + rl;                                              \
        const int d_ = (BUFOFF) + rl * 256 + ((u16 * 16) ^ ((rl & 7) << 4));   \
        ushort8v v_;                                                           \
        if (rG_ < 175) v_ = emb8(lds_raw, rG_ - C_, u16, sc);                  \
        else           v_ = (ushort8v)(unsigned short)0;                       \
        *(ushort8v*)(lds_raw + d_) = v_;                                       \
    }

#define MFMA2(c, BUFOFF)                                                       \
    {                                                                          \
        _Pragma("unroll")                                                      \
        for (int kk = 0; kk < 4; ++kk) {                                       \
            _Pragma("unroll")                                                  \
            for (int jj = 0; jj < 2; ++jj) {                                   \
                const int rr = jj * 16 + lr;                                   \
                const int byt = (BUFOFF) + rr * 256 +                          \
                                (((kk * 64) + (lk * 16)) ^ ((rr & 7) << 4));   \
                bf16x8 bf = __builtin_bit_cast(bf16x8,                         \
                                *(const ushort8v*)(lds_raw + byt));            \
                acc[2 * (c) + jj] = __builtin_amdgcn_mfma_f32_16x16x32_bf16(   \
                                        qf[kk], bf, acc[2 * (c) + jj], 0, 0, 0);\
            }                                                                  \
        }                                                                      \
    }

#define MFMA1(BUFOFF)                                                          \
    {                                                                          \
        _Pragma("unroll")                                                      \
        for (int kk = 0; kk < 4; ++kk) {                                       \
            const int byt = (BUFOFF) + lr * 256 +                              \
                            (((kk * 64) + (lk * 16)) ^ ((lr & 7) << 4));       \
            bf16x8 bf = __builtin_bit_cast(bf16x8,                             \
                            *(const ushort8v*)(lds_raw + byt));                \
            acc[10] = __builtin_amdgcn_mfma_f32_16x16x32_bf16(                 \
                          qf[kk], bf, acc[10], 0, 0, 0);                       \
        }                                                                      \
    }

#define STORE_TILE(J)                                                          \
    {                                                                          \
        const int c_ = (J) * 16 + lr;                                          \
        if (c_ < C_) {                                                         \
            _Pragma("unroll")                                                  \
            for (int reg = 0; reg < 4; ++reg) {                                \
                const int w_ = w0 + lk * 4 + reg;                              \
                const int wg_ = hbase + w_;                                    \
                float v_ = acc[J][reg];                                        \
                const int d_ = c_ - wg_;                                       \
                if (d_ >= 0 && d_ < SPAN) v_ += bf2f(bd[w_ * BD_PITCH + d_]);  \
                __builtin_nontemporal_store(v_, out + obase + (size_t)wg_ * C_ + c_); \
            }                                                                  \
        }                                                                      \
    }

__global__ __launch_bounds__(256, 4) void k_main(const float* __restrict__ q,
                                                 const float* __restrict__ k,
                                                 const float* __restrict__ part,
                                                 float* __restrict__ out, SC sc) {
    __shared__ __align__(16) char lds_raw[AUX_OFF + 3584];
    unsigned short* bd = (unsigned short*)(lds_raw + AUX_OFF);  // alias redp/s12

    const int bid = blockIdx.x;
    const int n = bid & 7;
    const int u = (bid >> 3) & 15;
    const int b = (bid >> 7) & 7;
    const int hbase = (bid >> 10) * 64;   // which 64-row Q half

    const size_t qbase = ((size_t)(b * U_ + u) * W_) * HID + n * HDIM;
    const size_t kbase = ((size_t)(b * U_ + u) * C_) * HID + n * HDIM;
    const size_t obase = ((size_t)((b * NHEADS + n) * U_ + u)) * (W_ * C_);

    const int tid = threadIdx.x;
    const int lane = tid & 63;
    const int wave = tid >> 6;      // 0..3
    const int w0 = wave * 16;       // local Q row base (0..48)
    const int lr = lane & 15;
    const int lk = lane >> 4;
    const int u16 = tid & 15;
    const int rl = tid >> 4;        // 0..15

    // ---- prologue: part sums, K ch4+ch0, Q
    const int c4 = tid & 31, rg = tid >> 5;    // c4 col-group, rg 0..7
    const float* pbase = part + n * HDIM + c4 * 4;
    float4 ps0 = *(const float4*)(pbase + (size_t)(rg * 8 + 0) * HID);
    float4 ps1 = *(const float4*)(pbase + (size_t)(rg * 8 + 1) * HID);
    #pragma unroll
    for (int i = 2; i < 8; i += 2) {
        float4 t0 = *(const float4*)(pbase + (size_t)(rg * 8 + i) * HID);
        float4 t1 = *(const float4*)(pbase + (size_t)(rg * 8 + i + 1) * HID);
        ps0.x += t0.x; ps0.y += t0.y; ps0.z += t0.z; ps0.w += t0.w;
        ps1.x += t1.x; ps1.y += t1.y; ps1.z += t1.z; ps1.w += t1.w;
    }

    float4 a0, a1, a2, a3, b0, b1, b2, b3;
    ISSUE_K(4, a0, a1, a2, a3);
    ISSUE_K(0, b0, b1, b2, b3);

    // Q load+convert (4 waves x 16 rows, row hbase+w0+lr)
    const float* qrow = q + qbase + (size_t)(hbase + w0 + lr) * HID + lk * 8;
    bf16x8 qf[4];
    #pragma unroll
    for (int kk = 0; kk < 4; ++kk) {
        float4 t0 = *(const float4*)(qrow + kk * 32);
        float4 t1 = *(const float4*)(qrow + kk * 32 + 4);
        qf[kk] = __builtin_bit_cast(bf16x8, cvt8(t0, t1));
    }

    // redp write: 8 rows x 128 cols bf16 at AUX_OFF
    {
        ps0.x += ps1.x; ps0.y += ps1.y; ps0.z += ps1.z; ps0.w += ps1.w;
        ushort4v rb;
        rb[0] = f2bf(ps0.x); rb[1] = f2bf(ps0.y); rb[2] = f2bf(ps0.z); rb[3] = f2bf(ps0.w);
        *(ushort4v*)(lds_raw + AUX_OFF + rg * 256 + c4 * 8) = rb;
    }
    BAR();   // redp ready (K/Q loads stay in flight)

    // s12 reduce: all 256 threads, col 0..127 x half
    {
        const int col = tid & 127, hs = tid >> 7;
        float s = 0.f;
        #pragma unroll
        for (int g = 0; g < 4; ++g)
            s += bf2f(*(const unsigned short*)(lds_raw + AUX_OFF + (hs * 4 + g) * 256 + col * 2));
        *(float*)(lds_raw + S12_OFF + (hs * 128 + col) * 4) = s;
    }

    f32x4 acc[11];
    #pragma unroll
    for (int j = 0; j < 11; ++j) acc[j] = (f32x4)(0.f);

    BAR();   // s12 ready

    WRITE_C4(a0, a1, a2, a3, 0);
    BAR();

    // P0: MFMA ch4 (tiles 8,9); stage ch5 -> buf1 (emb only); issue ch1
    MFMA2(4, 0);
    WRITE_C5(CHUNK_B);
    ISSUE_K(1, a0, a1, a2, a3);
    BAR();

    // P1: MFMA ch5 (tile 10); bd exchange; stage ch0 -> buf0; issue ch2
    MFMA1(CHUNK_B);
    {
        const int c9 = 144 + lr;
        if (c9 >= C_) {
            const int f = c9 - C_;
            #pragma unroll
            for (int reg = 0; reg < 4; ++reg) {
                const int w = w0 + lk * 4 + reg;
                bd[w * BD_PITCH + f] = f2bf(acc[9][reg]);
            }
        }
        const int f10 = 9 + lr;
        if (f10 < SPAN) {
            #pragma unroll
            for (int reg = 0; reg < 4; ++reg) {
                const int w = w0 + lk * 4 + reg;
                bd[w * BD_PITCH + f10] = f2bf(acc[10][reg]);
            }
        }
    }
    WRITE_PURE(b0, b1, b2, b3, 0);
    ISSUE_K(2, b0, b1, b2, b3);
    BAR();

    // P2: MFMA ch0; stage ch1 -> buf1; issue ch3; store tiles 8,9
    MFMA2(0, 0);
    WRITE_PURE(a0, a1, a2, a3, CHUNK_B);
    ISSUE_K(3, a0, a1, a2, a3);
    STORE_TILE(8);
    STORE_TILE(9);
    BAR();

    // P3: MFMA ch1; stage ch2 -> buf0; store tiles 0,1
    MFMA2(1, CHUNK_B);
    WRITE_PURE(b0, b1, b2, b3, 0);
    STORE_TILE(0);
    STORE_TILE(1);
    BAR();

    // P4: MFMA ch2; stage ch3 -> buf1; store tiles 2,3
    MFMA2(2, 0);
    WRITE_PURE(a0, a1, a2, a3, CHUNK_B);
    STORE_TILE(2);
    STORE_TILE(3);
    BAR();

    // P5: MFMA ch3; store remaining tiles
    MFMA2(3, CHUNK_B);
    STORE_TILE(4);
    STORE_TILE(5);
    STORE_TILE(6);
    STORE_TILE(7);
}

extern "C" void kernel_launch(void* const* d_in, const int* in_sizes, int n_in,
                              void* d_out, int out_size, void* d_ws, size_t ws_size,
                              hipStream_t stream) {
    const float* queries = (const float*)d_in[0];
    const float* keys    = (const float*)d_in[1];
    const float* posproj = (const float*)d_in[2];
    float* out = (float*)d_out;

    float* part = (float*)d_ws;      // 64*1024 f32 = 256 KB

    SC sc;
    for (int f = 0; f < SPAN; ++f) {
        float p = (float)(11 - f);   // MAX_BACKWARD..-MAX_FORWARD
        sc.s[f] = sinf(p);
        sc.c[f] = cosf(p);
    }

    k_partial<<<256, 64, 0, stream>>>(posproj, part);
    k_main<<<2048, 256, 0, stream>>>(queries, keys, part, out, sc);
}

// Round 11
// 96.424 us; speedup vs baseline: 1.0125x; 1.0125x over previous
//
#include <hip/hip_runtime.h>
#include <cmath>

#define NHEADS 8
#define HDIM 128
#define SPAN 24
#define U_ 16
#define W_ 128
#define C_ 151
#define HID 1024

typedef __bf16 bf16x8 __attribute__((ext_vector_type(8)));
typedef float f32x4 __attribute__((ext_vector_type(4)));

__device__ inline bf16x8 mk8(float4 a, float4 b) {
    bf16x8 v;
    v[0] = (__bf16)a.x; v[1] = (__bf16)a.y; v[2] = (__bf16)a.z; v[3] = (__bf16)a.w;
    v[4] = (__bf16)b.x; v[5] = (__bf16)b.y; v[6] = (__bf16)b.z; v[7] = (__bf16)b.w;
    return v;
}

// lgkm-only barrier: orders LDS producer->consumer without draining vmcnt.
#define BAR() asm volatile("s_waitcnt lgkmcnt(0)\n\ts_barrier" ::: "memory")

// ---- kernel 1: partial column sums of pos_proj (256 blocks x 64 thr) ----
__global__ void k_partial(const float* __restrict__ pp, float* __restrict__ part) {
    const int bi = blockIdx.x >> 2, cj = blockIdx.x & 3;
    const int col = cj * 256 + threadIdx.x * 4;
    const int row0 = bi * 16;
    float4 s = make_float4(0.f, 0.f, 0.f, 0.f);
    #pragma unroll
    for (int i = 0; i < 16; ++i) {
        float4 v = *(const float4*)(pp + (size_t)(row0 + i) * HID + col);
        s.x += v.x; s.y += v.y; s.z += v.z; s.w += v.w;
    }
    *(float4*)(part + (size_t)bi * HID + col) = s;
}

struct SC { float s[SPAN]; float c[SPAN]; };

// ---- main kernel: NO K LDS staging. Each wave reads its B-fragments
// directly from global (L2-resident 45 KB K slice, shared by the block's 8
// waves). Zero barriers after the tiny emb-synthesis prologue -> all
// resident waves are fully independent memory streams.
// INVARIANT: every MFMA is issued convergently (all 64 lanes). Mixed-source
// rows (tile 9) select the B-fragment per-lane into a register first.
// LDS: emb [25 rows][256B] swizzled @0 ; redp @6400 (4KB) ; s12 @10496 (1KB);
//      bd bf16 [128][25] @11520 (6400B). Total 17920 B.
#define EMB_OFF 0
#define REDP_OFF 6400
#define S12_OFF 10496
#define BD_OFF 11520
#define BD_PITCH 25

__device__ inline bf16x8 emb8(const char* lds_raw, int f, int u16, const SC& sc) {
    float4 s1a = *(const float4*)(lds_raw + S12_OFF + u16 * 32);
    float4 s1b = *(const float4*)(lds_raw + S12_OFF + u16 * 32 + 16);
    float4 s2a = *(const float4*)(lds_raw + S12_OFF + 512 + u16 * 32);
    float4 s2b = *(const float4*)(lds_raw + S12_OFF + 512 + u16 * 32 + 16);
    const float sf = sc.s[f], cf = sc.c[f];
    bf16x8 v;
    v[0] = (__bf16)(sf * s1a.x + cf * s2a.x); v[1] = (__bf16)(sf * s1a.y + cf * s2a.y);
    v[2] = (__bf16)(sf * s1a.z + cf * s2a.z); v[3] = (__bf16)(sf * s1a.w + cf * s2a.w);
    v[4] = (__bf16)(sf * s1b.x + cf * s2b.x); v[5] = (__bf16)(sf * s1b.y + cf * s2b.y);
    v[6] = (__bf16)(sf * s1b.z + cf * s2b.z); v[7] = (__bf16)(sf * s1b.w + cf * s2b.w);
    return v;
}

#define STORE_TILE(J)                                                          \
    {                                                                          \
        const int c_ = (J) * 16 + lr;                                          \
        if (c_ < C_) {                                                         \
            _Pragma("unroll")                                                  \
            for (int reg = 0; reg < 4; ++reg) {                                \
                const int w_ = w0 + lk * 4 + reg;                              \
                float v_ = acc[J][reg];                                        \
                const int d_ = c_ - w_;                                        \
                if (d_ >= 0 && d_ < SPAN) v_ += (float)bd[w_ * BD_PITCH + d_]; \
                out[obase + (size_t)w_ * C_ + c_] = v_;                        \
            }                                                                  \
        }                                                                      \
    }

__global__ __launch_bounds__(512, 4) void k_main(const float* __restrict__ q,
                                                 const float* __restrict__ k,
                                                 const float* __restrict__ part,
                                                 float* __restrict__ out, SC sc) {
    __shared__ __align__(16) char lds_raw[17920];
    __bf16* bd = (__bf16*)(lds_raw + BD_OFF);

    const int bid = blockIdx.x;
    const int n = bid & 7;
    const int u = (bid >> 3) & 15;
    const int b = bid >> 7;

    const size_t qbase = ((size_t)(b * U_ + u) * W_) * HID + n * HDIM;
    const size_t kbase = ((size_t)(b * U_ + u) * C_) * HID + n * HDIM;
    const size_t obase = ((size_t)((b * NHEADS + n) * U_ + u)) * (W_ * C_);

    const int tid = threadIdx.x;
    const int lane = tid & 63;
    const int wave = tid >> 6;      // 0..7, owns Q rows 16*wave..+15
    const int w0 = wave * 16;
    const int lr = lane & 15;
    const int lk = lane >> 4;

    // ---- prologue global loads (in flight across the emb-synthesis phase)
    const int c4 = tid & 31, rg = tid >> 5;   // rg 0..15
    float4 pp4[4];
    #pragma unroll
    for (int i = 0; i < 4; ++i)
        pp4[i] = *(const float4*)(part + (size_t)(rg * 4 + i) * HID + n * HDIM + c4 * 4);

    const float* qrow = q + qbase + (size_t)(w0 + lr) * HID + lk * 8;
    float4 qpf[8];
    #pragma unroll
    for (int kk = 0; kk < 4; ++kk) {
        qpf[2 * kk]     = *(const float4*)(qrow + kk * 32);
        qpf[2 * kk + 1] = *(const float4*)(qrow + kk * 32 + 4);
    }

    // ---- redp: 16 rows x 128 cols bf16
    {
        float4 rs;
        rs.x = pp4[0].x + pp4[1].x + pp4[2].x + pp4[3].x;
        rs.y = pp4[0].y + pp4[1].y + pp4[2].y + pp4[3].y;
        rs.z = pp4[0].z + pp4[1].z + pp4[2].z + pp4[3].z;
        rs.w = pp4[0].w + pp4[1].w + pp4[2].w + pp4[3].w;
        __bf16* rp = (__bf16*)(lds_raw + REDP_OFF) + rg * 128 + c4 * 4;
        rp[0] = (__bf16)rs.x; rp[1] = (__bf16)rs.y; rp[2] = (__bf16)rs.z; rp[3] = (__bf16)rs.w;
    }
    BAR();   // redp ready (Q loads stay in flight)

    // ---- s12 reduce (S1 = partial rows 0..31, S2 = 32..63)
    if (tid < 256) {
        const int col = tid & 127, half = tid >> 7;
        const __bf16* rp = (const __bf16*)(lds_raw + REDP_OFF);
        float s = 0.f;
        #pragma unroll
        for (int g = 0; g < 8; ++g) s += (float)rp[(half * 8 + g) * 128 + col];
        *(float*)(lds_raw + S12_OFF + (half * 128 + col) * 4) = s;
    }
    // Q convert overlaps barrier
    bf16x8 qf[4];
    #pragma unroll
    for (int kk = 0; kk < 4; ++kk)
        qf[kk] = mk8(qpf[2 * kk], qpf[2 * kk + 1]);
    BAR();   // s12 ready

    // ---- synthesize emb rows into LDS: e = 0..23 (global rows 151..174),
    // e = 24 is the zero row. 25 rows x 16 slots = 400 slots.
    {
        const int u16s = tid & 15;
        if (tid < 384) {
            const int e = tid >> 4;
            bf16x8 v = emb8(lds_raw, e, u16s, sc);
            const int dst = EMB_OFF + e * 256 + ((u16s * 16) ^ ((e & 7) << 4));
            *(bf16x8*)(lds_raw + dst) = v;
        } else if (tid < 400) {
            const int dst = EMB_OFF + 24 * 256 + (u16s * 16);  // e=24: e&7=0
            *(bf16x8*)(lds_raw + dst) = (bf16x8)(__bf16)0.f;
        }
    }
    BAR();   // emb ready — LAST barrier; waves fully independent from here

    f32x4 acc[11];
    #pragma unroll
    for (int j = 0; j < 11; ++j) acc[j] = (f32x4)(0.f);

    // ---- tile 9 (cols 144..159): rows 144..150 global K, 151..159 emb.
    // Per-lane fragment select into a register; MFMA issued convergently.
    {
        const int r = 144 + lr;
        const float* kr = k + kbase + (size_t)r * HID + lk * 8;  // valid iff r<C_
        const int e = lr - 7;                                    // valid iff r>=C_
        #pragma unroll
        for (int kk = 0; kk < 4; ++kk) {
            bf16x8 bf;
            if (r < C_) {
                float4 t0 = *(const float4*)(kr + kk * 32);
                float4 t1 = *(const float4*)(kr + kk * 32 + 4);
                bf = mk8(t0, t1);
            } else {
                const int byt = EMB_OFF + e * 256 + (((kk * 64) + (lk * 16)) ^ ((e & 7) << 4));
                bf = *(const bf16x8*)(lds_raw + byt);
            }
            acc[9] = __builtin_amdgcn_mfma_f32_16x16x32_bf16(qf[kk], bf, acc[9], 0, 0, 0);
        }
    }
    // ---- tile 10 (cols 160..175): all emb (e = 9..24; e=24 zero row) — uniform
    {
        const int e = 9 + lr;
        #pragma unroll
        for (int kk = 0; kk < 4; ++kk) {
            const int byt = EMB_OFF + e * 256 + (((kk * 64) + (lk * 16)) ^ ((e & 7) << 4));
            bf16x8 bf = *(const bf16x8*)(lds_raw + byt);
            acc[10] = __builtin_amdgcn_mfma_f32_16x16x32_bf16(qf[kk], bf, acc[10], 0, 0, 0);
        }
    }

    // ---- bd exchange (wave-private rows; lgkmcnt ordering only)
    {
        const int c9 = 144 + lr;
        if (c9 >= C_) {
            const int f = c9 - C_;
            #pragma unroll
            for (int reg = 0; reg < 4; ++reg) {
                const int w = w0 + lk * 4 + reg;
                bd[w * BD_PITCH + f] = (__bf16)acc[9][reg];
            }
        }
        const int f10 = 9 + lr;
        if (f10 < SPAN) {
            #pragma unroll
            for (int reg = 0; reg < 4; ++reg) {
                const int w = w0 + lk * 4 + reg;
                bd[w * BD_PITCH + f10] = (__bf16)acc[10][reg];
            }
        }
    }

    // ---- store tile 9 (needs bd)
    STORE_TILE(9);

    // ---- tiles 0..8: pure global-K fragments (uniform); store as computed
    #pragma unroll
    for (int j = 0; j < 9; ++j) {
        const int r = j * 16 + lr;    // <= 143 < C_
        const float* kr = k + kbase + (size_t)r * HID + lk * 8;
        #pragma unroll
        for (int kk = 0; kk < 4; ++kk) {
            float4 t0 = *(const float4*)(kr + kk * 32);
            float4 t1 = *(const float4*)(kr + kk * 32 + 4);
            acc[j] = __builtin_amdgcn_mfma_f32_16x16x32_bf16(qf[kk], mk8(t0, t1), acc[j], 0, 0, 0);
        }
        STORE_TILE(j);
    }
}

extern "C" void kernel_launch(void* const* d_in, const int* in_sizes, int n_in,
                              void* d_out, int out_size, void* d_ws, size_t ws_size,
                              hipStream_t stream) {
    const float* queries = (const float*)d_in[0];
    const float* keys    = (const float*)d_in[1];
    const float* posproj = (const float*)d_in[2];
    float* out = (float*)d_out;

    float* part = (float*)d_ws;      // 64*1024 f32 = 256 KB

    SC sc;
    for (int f = 0; f < SPAN; ++f) {
        float p = (float)(11 - f);   // MAX_BACKWARD..-MAX_FORWARD
        sc.s[f] = sinf(p);
        sc.c[f] = cosf(p);
    }

    k_partial<<<256, 64, 0, stream>>>(posproj, part);
    k_main<<<1024, 512, 0, stream>>>(queries, keys, part, out, sc);
}

// Round 12
// 90.332 us; speedup vs baseline: 1.0808x; 1.0674x over previous
//
#include <hip/hip_runtime.h>
#include <cmath>

#define NHEADS 8
#define HDIM 128
#define SPAN 24
#define U_ 16
#define W_ 128
#define C_ 151
#define HID 1024

typedef unsigned short ushort8v __attribute__((ext_vector_type(8)));
typedef unsigned short ushort4v __attribute__((ext_vector_type(4)));
typedef __bf16 bf16x8 __attribute__((ext_vector_type(8)));
typedef float f32x4 __attribute__((ext_vector_type(4)));

__device__ inline unsigned short f2bf(float f) {
    union { float f; unsigned u; } v; v.f = f;
    unsigned r = v.u + 0x7FFFu + ((v.u >> 16) & 1u);
    return (unsigned short)(r >> 16);
}
__device__ inline float bf2f(unsigned short u) {
    union { unsigned u; float f; } v; v.u = ((unsigned)u) << 16;
    return v.f;
}
__device__ inline ushort8v cvt8(float4 a, float4 b) {
    ushort8v v;
    v[0] = f2bf(a.x); v[1] = f2bf(a.y); v[2] = f2bf(a.z); v[3] = f2bf(a.w);
    v[4] = f2bf(b.x); v[5] = f2bf(b.y); v[6] = f2bf(b.z); v[7] = f2bf(b.w);
    return v;
}

// lgkm-only barrier: orders LDS producer->consumer without draining vmcnt.
#define BAR() asm volatile("s_waitcnt lgkmcnt(0)\n\ts_barrier" ::: "memory")

// ---- kernel 1: partial column sums of pos_proj (256 blocks x 64 thr) ----
__global__ void k_partial(const float* __restrict__ pp, float* __restrict__ part) {
    const int bi = blockIdx.x >> 2, cj = blockIdx.x & 3;
    const int col = cj * 256 + threadIdx.x * 4;
    const int row0 = bi * 16;
    float4 s = make_float4(0.f, 0.f, 0.f, 0.f);
    #pragma unroll
    for (int i = 0; i < 16; ++i) {
        float4 v = *(const float4*)(pp + (size_t)(row0 + i) * HID + col);
        s.x += v.x; s.y += v.y; s.z += v.z; s.w += v.w;
    }
    *(float4*)(part + (size_t)bi * HID + col) = s;
}

struct SC { float s[SPAN]; float c[SPAN]; };

// ---- main kernel: chunked dbuf pipeline, chunk order [4,5,0,1,2,3],
// lgkm-only barriers (loads never drained), stores streamed into the loop,
// NONTEMPORAL output stores (output never re-read; keep Q/K L3-resident).
// LDS: buf0 [0,8192) buf1 [8192,16384) aux/bd [16384, 22784).
#define CHUNK_B 8192
#define AUX_OFF 16384
#define S12_OFF (AUX_OFF + 4096)
#define BD_PITCH 25

__device__ inline ushort8v emb8(const char* lds_raw, int f, int u16, const SC& sc) {
    float4 s1a = *(const float4*)(lds_raw + S12_OFF + u16 * 32);
    float4 s1b = *(const float4*)(lds_raw + S12_OFF + u16 * 32 + 16);
    float4 s2a = *(const float4*)(lds_raw + S12_OFF + 512 + u16 * 32);
    float4 s2b = *(const float4*)(lds_raw + S12_OFF + 512 + u16 * 32 + 16);
    const float sf = sc.s[f], cf = sc.c[f];
    ushort8v v;
    v[0] = f2bf(sf * s1a.x + cf * s2a.x); v[1] = f2bf(sf * s1a.y + cf * s2a.y);
    v[2] = f2bf(sf * s1a.z + cf * s2a.z); v[3] = f2bf(sf * s1a.w + cf * s2a.w);
    v[4] = f2bf(sf * s1b.x + cf * s2b.x); v[5] = f2bf(sf * s1b.y + cf * s2b.y);
    v[6] = f2bf(sf * s1b.z + cf * s2b.z); v[7] = f2bf(sf * s1b.w + cf * s2b.w);
    return v;
}

#define ISSUE_K(c, P0, P1)                                                     \
    {                                                                          \
        const int r_ = 32 * (c) + (tid >> 4);                                  \
        if (r_ < C_) {                                                         \
            const float* s_ = k + kbase + (size_t)r_ * HID + u16 * 8;          \
            P0 = *(const float4*)s_; P1 = *(const float4*)(s_ + 4);            \
        }                                                                      \
    }

#define WRITE_PURE(P0, P1, BUFOFF)                                             \
    {                                                                          \
        const int rl_ = tid >> 4;                                              \
        const int dst_ = (BUFOFF) + rl_ * 256 + ((u16 * 16) ^ ((rl_ & 7) << 4));\
        *(ushort8v*)(lds_raw + dst_) = cvt8(P0, P1);                           \
    }

// chunk 4: rows 128..150 are K, 151..159 are emb
#define WRITE_C4(P0, P1, BUFOFF)                                               \
    {                                                                          \
        const int rl_ = tid >> 4;                                              \
        const int r_ = 128 + rl_;                                              \
        const int dst_ = (BUFOFF) + rl_ * 256 + ((u16 * 16) ^ ((rl_ & 7) << 4));\
        ushort8v v_;                                                           \
        if (r_ < C_) v_ = cvt8(P0, P1);                                        \
        else         v_ = emb8(lds_raw, r_ - C_, u16, sc);                     \
        *(ushort8v*)(lds_raw + dst_) = v_;                                     \
    }

// chunk 5: rows 160..174 emb, 175 zero; only tid<256 (no global data at all)
#define WRITE_C5(BUFOFF)                                                       \
    if (tid < 256) {                                                           \
        const int rl_ = tid >> 4;                                              \
        const int r_ = 160 + rl_;                                              \
        const int dst_ = (BUFOFF) + rl_ * 256 + ((u16 * 16) ^ ((rl_ & 7) << 4));\
        ushort8v v_;                                                           \
        if (r_ < 175) v_ = emb8(lds_raw, r_ - C_, u16, sc);                    \
        else          v_ = (ushort8v)(unsigned short)0;                        \
        *(ushort8v*)(lds_raw + dst_) = v_;                                     \
    }

#define MFMA2(c, BUFOFF)                                                       \
    {                                                                          \
        _Pragma("unroll")                                                      \
        for (int kk = 0; kk < 4; ++kk) {                                       \
            _Pragma("unroll")                                                  \
            for (int jj = 0; jj < 2; ++jj) {                                   \
                const int rl = jj * 16 + lr;                                   \
                const int byt = (BUFOFF) + rl * 256 +                          \
                                (((kk * 64) + (lk * 16)) ^ ((rl & 7) << 4));   \
                bf16x8 bf = __builtin_bit_cast(bf16x8,                         \
                                *(const ushort8v*)(lds_raw + byt));            \
                acc[2 * (c) + jj] = __builtin_amdgcn_mfma_f32_16x16x32_bf16(   \
                                        qf[kk], bf, acc[2 * (c) + jj], 0, 0, 0);\
            }                                                                  \
        }                                                                      \
    }

#define MFMA1(BUFOFF)                                                          \
    {                                                                          \
        _Pragma("unroll")                                                      \
        for (int kk = 0; kk < 4; ++kk) {                                       \
            const int rl = lr;                                                 \
            const int byt = (BUFOFF) + rl * 256 +                              \
                            (((kk * 64) + (lk * 16)) ^ ((rl & 7) << 4));       \
            bf16x8 bf = __builtin_bit_cast(bf16x8,                             \
                            *(const ushort8v*)(lds_raw + byt));                \
            acc[10] = __builtin_amdgcn_mfma_f32_16x16x32_bf16(                 \
                          qf[kk], bf, acc[10], 0, 0, 0);                       \
        }                                                                      \
    }

#define STORE_TILE(J)                                                          \
    {                                                                          \
        const int c_ = (J) * 16 + lr;                                          \
        if (c_ < C_) {                                                         \
            _Pragma("unroll")                                                  \
            for (int reg = 0; reg < 4; ++reg) {                                \
                const int w_ = w0 + lk * 4 + reg;                              \
                float v_ = acc[J][reg];                                        \
                const int d_ = c_ - w_;                                        \
                if (d_ >= 0 && d_ < SPAN) v_ += bf2f(bd[w_ * BD_PITCH + d_]);  \
                __builtin_nontemporal_store(v_, out + obase + (size_t)w_ * C_ + c_); \
            }                                                                  \
        }                                                                      \
    }

__global__ __launch_bounds__(512, 4) void k_main(const float* __restrict__ q,
                                                 const float* __restrict__ k,
                                                 const float* __restrict__ part,
                                                 float* __restrict__ out, SC sc) {
    __shared__ __align__(16) char lds_raw[AUX_OFF + W_ * BD_PITCH * 2];
    unsigned short* bd = (unsigned short*)(lds_raw + AUX_OFF);  // alias redp/s12

    const int bid = blockIdx.x;
    const int n = bid & 7;
    const int u = (bid >> 3) & 15;
    const int b = bid >> 7;

    const size_t qbase = ((size_t)(b * U_ + u) * W_) * HID + n * HDIM;
    const size_t kbase = ((size_t)(b * U_ + u) * C_) * HID + n * HDIM;
    const size_t obase = ((size_t)((b * NHEADS + n) * U_ + u)) * (W_ * C_);

    const int tid = threadIdx.x;
    const int lane = tid & 63;
    const int wave = tid >> 6;
    const int w0 = wave * 16;
    const int lr = lane & 15;
    const int lk = lane >> 4;
    const int u16 = tid & 15;

    // ---- prologue: issue pp4, Q, chunk4, chunk0 loads (in this age order)
    const int c4 = tid & 31, rg = tid >> 5;
    float4 pp4[4];
    #pragma unroll
    for (int i = 0; i < 4; ++i)
        pp4[i] = *(const float4*)(part + (size_t)(rg * 4 + i) * HID + n * HDIM + c4 * 4);

    const float* qrow = q + qbase + (size_t)(w0 + lr) * HID + lk * 8;
    float4 qpf[8];
    #pragma unroll
    for (int kk = 0; kk < 4; ++kk) {
        qpf[2 * kk]     = *(const float4*)(qrow + kk * 32);
        qpf[2 * kk + 1] = *(const float4*)(qrow + kk * 32 + 4);
    }

    float4 a0, a1, b0, b1;
    ISSUE_K(4, a0, a1);     // rows 128..150 predicated
    ISSUE_K(0, b0, b1);

    // redp partial reduce + LDS write
    {
        float4 rs;
        rs.x = pp4[0].x + pp4[1].x + pp4[2].x + pp4[3].x;
        rs.y = pp4[0].y + pp4[1].y + pp4[2].y + pp4[3].y;
        rs.z = pp4[0].z + pp4[1].z + pp4[2].z + pp4[3].z;
        rs.w = pp4[0].w + pp4[1].w + pp4[2].w + pp4[3].w;
        ushort4v rb;
        rb[0] = f2bf(rs.x); rb[1] = f2bf(rs.y); rb[2] = f2bf(rs.z); rb[3] = f2bf(rs.w);
        *(ushort4v*)(lds_raw + AUX_OFF + rg * 256 + c4 * 8) = rb;
    }
    BAR();   // redp ready (global loads stay in flight)

    // s12 reduce; Q convert overlaps
    if (tid < 256) {
        const int col = tid & 127, half = tid >> 7;
        float s = 0.f;
        #pragma unroll
        for (int g = 0; g < 8; ++g)
            s += bf2f(*(const unsigned short*)(lds_raw + AUX_OFF + (half * 8 + g) * 256 + col * 2));
        *(float*)(lds_raw + S12_OFF + (half * 128 + col) * 4) = s;
    }
    bf16x8 qf[4];
    #pragma unroll
    for (int kk = 0; kk < 4; ++kk)
        qf[kk] = __builtin_bit_cast(bf16x8, cvt8(qpf[2 * kk], qpf[2 * kk + 1]));

    f32x4 acc[11];
    #pragma unroll
    for (int j = 0; j < 11; ++j) acc[j] = (f32x4)(0.f);

    BAR();   // s12 ready

    // ---- pre-loop: stage chunk4 (K rows 128..150 + emb 151..159) -> buf0
    WRITE_C4(a0, a1, 0);
    BAR();

    // P0: MFMA ch4; stage ch5 -> buf1 (emb only); issue ch1
    MFMA2(4, 0);
    WRITE_C5(CHUNK_B);
    ISSUE_K(1, a0, a1);
    BAR();

    // P1: MFMA ch5; bd exchange (wave-private, aux now dead); stage ch0 -> buf0; issue ch2
    MFMA1(CHUNK_B);
    {
        const int c9 = 144 + lr;
        if (c9 >= C_) {
            const int f = c9 - C_;
            #pragma unroll
            for (int reg = 0; reg < 4; ++reg) {
                const int w = w0 + lk * 4 + reg;
                bd[w * BD_PITCH + f] = f2bf(acc[9][reg]);
            }
        }
        const int f10 = 9 + lr;
        if (f10 < SPAN) {
            #pragma unroll
            for (int reg = 0; reg < 4; ++reg) {
                const int w = w0 + lk * 4 + reg;
                bd[w * BD_PITCH + f10] = f2bf(acc[10][reg]);
            }
        }
    }
    WRITE_PURE(b0, b1, 0);
    ISSUE_K(2, b0, b1);
    BAR();

    // P2: MFMA ch0; stage ch1 -> buf1; issue ch3; store tiles 8,9
    MFMA2(0, 0);
    WRITE_PURE(a0, a1, CHUNK_B);
    ISSUE_K(3, a0, a1);
    STORE_TILE(8);
    STORE_TILE(9);
    BAR();

    // P3: MFMA ch1; stage ch2 -> buf0; store tiles 0,1
    MFMA2(1, CHUNK_B);
    WRITE_PURE(b0, b1, 0);
    STORE_TILE(0);
    STORE_TILE(1);
    BAR();

    // P4: MFMA ch2; stage ch3 -> buf1; store tiles 2,3
    MFMA2(2, 0);
    WRITE_PURE(a0, a1, CHUNK_B);
    STORE_TILE(2);
    STORE_TILE(3);
    BAR();

    // P5: MFMA ch3; store tiles 4,5 (no further LDS writes -> no barrier)
    MFMA2(3, CHUNK_B);
    STORE_TILE(4);
    STORE_TILE(5);

    // epilogue
    STORE_TILE(6);
    STORE_TILE(7);
}

extern "C" void kernel_launch(void* const* d_in, const int* in_sizes, int n_in,
                              void* d_out, int out_size, void* d_ws, size_t ws_size,
                              hipStream_t stream) {
    const float* queries = (const float*)d_in[0];
    const float* keys    = (const float*)d_in[1];
    const float* posproj = (const float*)d_in[2];
    float* out = (float*)d_out;

    float* part = (float*)d_ws;      // 64*1024 f32 = 256 KB

    SC sc;
    for (int f = 0; f < SPAN; ++f) {
        float p = (float)(11 - f);   // MAX_BACKWARD..-MAX_FORWARD
        sc.s[f] = sinf(p);
        sc.c[f] = cosf(p);
    }

    k_partial<<<256, 64, 0, stream>>>(posproj, part);
    k_main<<<1024, 512, 0, stream>>>(queries, keys, part, out, sc);
}

// Round 13
// 50.509 us; speedup vs baseline: 1.9329x; 1.7884x over previous
//
#include <hip/hip_runtime.h>
#include <cmath>

#define NHEADS 8
#define HDIM 128
#define SPAN 24
#define U_ 16
#define W_ 128
#define C_ 151
#define HID 1024

typedef unsigned short ushort8v __attribute__((ext_vector_type(8)));
typedef unsigned short ushort4v __attribute__((ext_vector_type(4)));
typedef __bf16 bf16x8 __attribute__((ext_vector_type(8)));
typedef float f32x4 __attribute__((ext_vector_type(4)));

__device__ inline unsigned short f2bf(float f) {
    union { float f; unsigned u; } v; v.f = f;
    unsigned r = v.u + 0x7FFFu + ((v.u >> 16) & 1u);
    return (unsigned short)(r >> 16);
}
__device__ inline float bf2f(unsigned short u) {
    union { unsigned u; float f; } v; v.u = ((unsigned)u) << 16;
    return v.f;
}
__device__ inline ushort8v cvt8(float4 a, float4 b) {
    ushort8v v;
    v[0] = f2bf(a.x); v[1] = f2bf(a.y); v[2] = f2bf(a.z); v[3] = f2bf(a.w);
    v[4] = f2bf(b.x); v[5] = f2bf(b.y); v[6] = f2bf(b.z); v[7] = f2bf(b.w);
    return v;
}

// lgkm-only barrier: orders LDS producer->consumer without draining vmcnt.
#define BAR() asm volatile("s_waitcnt lgkmcnt(0)\n\ts_barrier" ::: "memory")

// ---- kernel 1: partial column sums of pos_proj (256 blocks x 64 thr) ----
__global__ void k_partial(const float* __restrict__ pp, float* __restrict__ part) {
    const int bi = blockIdx.x >> 2, cj = blockIdx.x & 3;
    const int col = cj * 256 + threadIdx.x * 4;
    const int row0 = bi * 16;
    float4 s = make_float4(0.f, 0.f, 0.f, 0.f);
    #pragma unroll
    for (int i = 0; i < 16; ++i) {
        float4 v = *(const float4*)(pp + (size_t)(row0 + i) * HID + col);
        s.x += v.x; s.y += v.y; s.z += v.z; s.w += v.w;
    }
    *(float4*)(part + (size_t)bi * HID + col) = s;
}

struct SC { float s[SPAN]; float c[SPAN]; };

// ---- main kernel: chunked dbuf pipeline, chunk order [4,5,0,1,2,3],
// lgkm-only barriers (loads never drained), stores streamed into the loop.
// __launch_bounds__(512,6): cap combined regs at ~85 -> 3 blocks/CU.
// LDS: buf0 [0,8192) buf1 [8192,16384) aux/bd [16384, 22784).
#define CHUNK_B 8192
#define AUX_OFF 16384
#define S12_OFF (AUX_OFF + 4096)
#define BD_PITCH 25

__device__ inline ushort8v emb8(const char* lds_raw, int f, int u16, const SC& sc) {
    float4 s1a = *(const float4*)(lds_raw + S12_OFF + u16 * 32);
    float4 s1b = *(const float4*)(lds_raw + S12_OFF + u16 * 32 + 16);
    float4 s2a = *(const float4*)(lds_raw + S12_OFF + 512 + u16 * 32);
    float4 s2b = *(const float4*)(lds_raw + S12_OFF + 512 + u16 * 32 + 16);
    const float sf = sc.s[f], cf = sc.c[f];
    ushort8v v;
    v[0] = f2bf(sf * s1a.x + cf * s2a.x); v[1] = f2bf(sf * s1a.y + cf * s2a.y);
    v[2] = f2bf(sf * s1a.z + cf * s2a.z); v[3] = f2bf(sf * s1a.w + cf * s2a.w);
    v[4] = f2bf(sf * s1b.x + cf * s2b.x); v[5] = f2bf(sf * s1b.y + cf * s2b.y);
    v[6] = f2bf(sf * s1b.z + cf * s2b.z); v[7] = f2bf(sf * s1b.w + cf * s2b.w);
    return v;
}

#define ISSUE_K(c, P0, P1)                                                     \
    {                                                                          \
        const int r_ = 32 * (c) + (tid >> 4);                                  \
        if (r_ < C_) {                                                         \
            const float* s_ = k + kbase + (size_t)r_ * HID + u16 * 8;          \
            P0 = *(const float4*)s_; P1 = *(const float4*)(s_ + 4);            \
        }                                                                      \
    }

#define WRITE_PURE(P0, P1, BUFOFF)                                             \
    {                                                                          \
        const int rl_ = tid >> 4;                                              \
        const int dst_ = (BUFOFF) + rl_ * 256 + ((u16 * 16) ^ ((rl_ & 7) << 4));\
        *(ushort8v*)(lds_raw + dst_) = cvt8(P0, P1);                           \
    }

// chunk 4: rows 128..150 are K, 151..159 are emb
#define WRITE_C4(P0, P1, BUFOFF)                                               \
    {                                                                          \
        const int rl_ = tid >> 4;                                              \
        const int r_ = 128 + rl_;                                              \
        const int dst_ = (BUFOFF) + rl_ * 256 + ((u16 * 16) ^ ((rl_ & 7) << 4));\
        ushort8v v_;                                                           \
        if (r_ < C_) v_ = cvt8(P0, P1);                                        \
        else         v_ = emb8(lds_raw, r_ - C_, u16, sc);                     \
        *(ushort8v*)(lds_raw + dst_) = v_;                                     \
    }

// chunk 5: rows 160..174 emb, 175 zero; only tid<256 (no global data at all)
#define WRITE_C5(BUFOFF)                                                       \
    if (tid < 256) {                                                           \
        const int rl_ = tid >> 4;                                              \
        const int r_ = 160 + rl_;                                              \
        const int dst_ = (BUFOFF) + rl_ * 256 + ((u16 * 16) ^ ((rl_ & 7) << 4));\
        ushort8v v_;                                                           \
        if (r_ < 175) v_ = emb8(lds_raw, r_ - C_, u16, sc);                    \
        else          v_ = (ushort8v)(unsigned short)0;                        \
        *(ushort8v*)(lds_raw + dst_) = v_;                                     \
    }

#define MFMA2(c, BUFOFF)                                                       \
    {                                                                          \
        _Pragma("unroll")                                                      \
        for (int kk = 0; kk < 4; ++kk) {                                       \
            _Pragma("unroll")                                                  \
            for (int jj = 0; jj < 2; ++jj) {                                   \
                const int rl = jj * 16 + lr;                                   \
                const int byt = (BUFOFF) + rl * 256 +                          \
                                (((kk * 64) + (lk * 16)) ^ ((rl & 7) << 4));   \
                bf16x8 bf = __builtin_bit_cast(bf16x8,                         \
                                *(const ushort8v*)(lds_raw + byt));            \
                acc[2 * (c) + jj] = __builtin_amdgcn_mfma_f32_16x16x32_bf16(   \
                                        qf[kk], bf, acc[2 * (c) + jj], 0, 0, 0);\
            }                                                                  \
        }                                                                      \
    }

#define MFMA1(BUFOFF)                                                          \
    {                                                                          \
        _Pragma("unroll")                                                      \
        for (int kk = 0; kk < 4; ++kk) {                                       \
            const int rl = lr;                                                 \
            const int byt = (BUFOFF) + rl * 256 +                              \
                            (((kk * 64) + (lk * 16)) ^ ((rl & 7) << 4));       \
            bf16x8 bf = __builtin_bit_cast(bf16x8,                             \
                            *(const ushort8v*)(lds_raw + byt));                \
            acc[10] = __builtin_amdgcn_mfma_f32_16x16x32_bf16(                 \
                          qf[kk], bf, acc[10], 0, 0, 0);                       \
        }                                                                      \
    }

#define STORE_TILE(J)                                                          \
    {                                                                          \
        const int c_ = (J) * 16 + lr;                                          \
        if (c_ < C_) {                                                         \
            _Pragma("unroll")                                                  \
            for (int reg = 0; reg < 4; ++reg) {                                \
                const int w_ = w0 + lk * 4 + reg;                              \
                float v_ = acc[J][reg];                                        \
                const int d_ = c_ - w_;                                        \
                if (d_ >= 0 && d_ < SPAN) v_ += bf2f(bd[w_ * BD_PITCH + d_]);  \
                out[obase + (size_t)w_ * C_ + c_] = v_;                        \
            }                                                                  \
        }                                                                      \
    }

__global__ __launch_bounds__(512, 6) void k_main(const float* __restrict__ q,
                                                 const float* __restrict__ k,
                                                 const float* __restrict__ part,
                                                 float* __restrict__ out, SC sc) {
    __shared__ __align__(16) char lds_raw[AUX_OFF + W_ * BD_PITCH * 2];
    unsigned short* bd = (unsigned short*)(lds_raw + AUX_OFF);  // alias redp/s12

    const int bid = blockIdx.x;
    const int n = bid & 7;
    const int u = (bid >> 3) & 15;
    const int b = bid >> 7;

    const size_t qbase = ((size_t)(b * U_ + u) * W_) * HID + n * HDIM;
    const size_t kbase = ((size_t)(b * U_ + u) * C_) * HID + n * HDIM;
    const size_t obase = ((size_t)((b * NHEADS + n) * U_ + u)) * (W_ * C_);

    const int tid = threadIdx.x;
    const int lane = tid & 63;
    const int wave = tid >> 6;
    const int w0 = wave * 16;
    const int lr = lane & 15;
    const int lk = lane >> 4;
    const int u16 = tid & 15;

    // ---- prologue: issue pp4, Q, chunk4, chunk0 loads (in this age order)
    const int c4 = tid & 31, rg = tid >> 5;
    float4 pp4[4];
    #pragma unroll
    for (int i = 0; i < 4; ++i)
        pp4[i] = *(const float4*)(part + (size_t)(rg * 4 + i) * HID + n * HDIM + c4 * 4);

    const float* qrow = q + qbase + (size_t)(w0 + lr) * HID + lk * 8;
    float4 qpf[8];
    #pragma unroll
    for (int kk = 0; kk < 4; ++kk) {
        qpf[2 * kk]     = *(const float4*)(qrow + kk * 32);
        qpf[2 * kk + 1] = *(const float4*)(qrow + kk * 32 + 4);
    }

    float4 a0, a1, b0, b1;
    ISSUE_K(4, a0, a1);     // rows 128..150 predicated
    ISSUE_K(0, b0, b1);

    // redp partial reduce + LDS write
    {
        float4 rs;
        rs.x = pp4[0].x + pp4[1].x + pp4[2].x + pp4[3].x;
        rs.y = pp4[0].y + pp4[1].y + pp4[2].y + pp4[3].y;
        rs.z = pp4[0].z + pp4[1].z + pp4[2].z + pp4[3].z;
        rs.w = pp4[0].w + pp4[1].w + pp4[2].w + pp4[3].w;
        ushort4v rb;
        rb[0] = f2bf(rs.x); rb[1] = f2bf(rs.y); rb[2] = f2bf(rs.z); rb[3] = f2bf(rs.w);
        *(ushort4v*)(lds_raw + AUX_OFF + rg * 256 + c4 * 8) = rb;
    }
    BAR();   // redp ready (global loads stay in flight)

    // s12 reduce; Q convert overlaps
    if (tid < 256) {
        const int col = tid & 127, half = tid >> 7;
        float s = 0.f;
        #pragma unroll
        for (int g = 0; g < 8; ++g)
            s += bf2f(*(const unsigned short*)(lds_raw + AUX_OFF + (half * 8 + g) * 256 + col * 2));
        *(float*)(lds_raw + S12_OFF + (half * 128 + col) * 4) = s;
    }
    bf16x8 qf[4];
    #pragma unroll
    for (int kk = 0; kk < 4; ++kk)
        qf[kk] = __builtin_bit_cast(bf16x8, cvt8(qpf[2 * kk], qpf[2 * kk + 1]));

    f32x4 acc[11];
    #pragma unroll
    for (int j = 0; j < 11; ++j) acc[j] = (f32x4)(0.f);

    BAR();   // s12 ready

    // ---- pre-loop: stage chunk4 (K rows 128..150 + emb 151..159) -> buf0
    WRITE_C4(a0, a1, 0);
    BAR();

    // P0: MFMA ch4; stage ch5 -> buf1 (emb only); issue ch1
    MFMA2(4, 0);
    WRITE_C5(CHUNK_B);
    ISSUE_K(1, a0, a1);
    BAR();

    // P1: MFMA ch5; bd exchange (wave-private, aux now dead); stage ch0 -> buf0; issue ch2
    MFMA1(CHUNK_B);
    {
        const int c9 = 144 + lr;
        if (c9 >= C_) {
            const int f = c9 - C_;
            #pragma unroll
            for (int reg = 0; reg < 4; ++reg) {
                const int w = w0 + lk * 4 + reg;
                bd[w * BD_PITCH + f] = f2bf(acc[9][reg]);
            }
        }
        const int f10 = 9 + lr;
        if (f10 < SPAN) {
            #pragma unroll
            for (int reg = 0; reg < 4; ++reg) {
                const int w = w0 + lk * 4 + reg;
                bd[w * BD_PITCH + f10] = f2bf(acc[10][reg]);
            }
        }
    }
    WRITE_PURE(b0, b1, 0);
    ISSUE_K(2, b0, b1);
    BAR();

    // P2: MFMA ch0; stage ch1 -> buf1; issue ch3; store tiles 8,9
    MFMA2(0, 0);
    WRITE_PURE(a0, a1, CHUNK_B);
    ISSUE_K(3, a0, a1);
    STORE_TILE(8);
    STORE_TILE(9);
    BAR();

    // P3: MFMA ch1; stage ch2 -> buf0; store tiles 0,1
    MFMA2(1, CHUNK_B);
    WRITE_PURE(b0, b1, 0);
    STORE_TILE(0);
    STORE_TILE(1);
    BAR();

    // P4: MFMA ch2; stage ch3 -> buf1; store tiles 2,3
    MFMA2(2, 0);
    WRITE_PURE(a0, a1, CHUNK_B);
    STORE_TILE(2);
    STORE_TILE(3);
    BAR();

    // P5: MFMA ch3; store tiles 4,5 (no further LDS writes -> no barrier)
    MFMA2(3, CHUNK_B);
    STORE_TILE(4);
    STORE_TILE(5);

    // epilogue
    STORE_TILE(6);
    STORE_TILE(7);
}

extern "C" void kernel_launch(void* const* d_in, const int* in_sizes, int n_in,
                              void* d_out, int out_size, void* d_ws, size_t ws_size,
                              hipStream_t stream) {
    const float* queries = (const float*)d_in[0];
    const float* keys    = (const float*)d_in[1];
    const float* posproj = (const float*)d_in[2];
    float* out = (float*)d_out;

    float* part = (float*)d_ws;      // 64*1024 f32 = 256 KB

    SC sc;
    for (int f = 0; f < SPAN; ++f) {
        float p = (float)(11 - f);   // MAX_BACKWARD..-MAX_FORWARD
        sc.s[f] = sinf(p);
        sc.c[f] = cosf(p);
    }

    k_partial<<<256, 64, 0, stream>>>(posproj, part);
    k_main<<<1024, 512, 0, stream>>>(queries, keys, part, out, sc);
}